// Round 8
// baseline (236.709 us; speedup 1.0000x reference)
//
#include <hip/hip_runtime.h>

#define NUSERS  6041
#define NMOVIES 3953
#define EMB     32
#define NGEN    18
#define H1N     64
#define H2N     32
#define H3N     16

typedef __bf16 bf16_t;
typedef bf16_t bf16x8 __attribute__((ext_vector_type(8)));
typedef float  f32x4  __attribute__((ext_vector_type(4)));

__device__ __forceinline__ f32x4 mfma16(bf16x8 a, bf16x8 b, f32x4 c) {
    return __builtin_amdgcn_mfma_f32_16x16x32_bf16(a, b, c, 0, 0, 0);
}

// ---- fast f32->bf16, round-half-up (== RNE except exact .5 ulp midpoints).
// (bf16_t) casts compile to ~5-inst RNE chains on gfx950 (no hw cvt);
// bits+0x8000 then v_perm_b32 packs TWO elements in 3 insts total.
__device__ __forceinline__ unsigned pkh(float lo, float hi) {
    unsigned a = __float_as_uint(lo) + 0x8000u;
    unsigned b = __float_as_uint(hi) + 0x8000u;
    return __builtin_amdgcn_perm(b, a, 0x07060302u);   // {b.hi16, a.hi16}
}
__device__ __forceinline__ unsigned short pks(float x) {
    return (unsigned short)((__float_as_uint(x) + 0x8000u) >> 16);
}
__device__ __forceinline__ bf16x8 mk8(float e0, float e1, float e2, float e3,
                                      float e4, float e5, float e6, float e7) {
    union { unsigned u[4]; bf16x8 v; } r;
    r.u[0] = pkh(e0, e1); r.u[1] = pkh(e2, e3);
    r.u[2] = pkh(e4, e5); r.u[3] = pkh(e6, e7);
    return r.v;
}

// Ordering fence for LDS write->read (TBAA-distinct access types). The asm
// memory clobber is a compiler-level barrier at both IR and MIR level (fixed
// r5's nondeterminism). r7 also had sched_barrier(0) here; dropped — it
// pinned the post-RA scheduler and blocked interleaving around the fences.
__device__ __forceinline__ void lds_fence() {
    __asm__ volatile("" ::: "memory");
}

// bf16 LDS buffers, per wave. Column-pair packing permutation:
// h1 col c (c<32): feature (c&1)*16 + (c>>1); c>=32: 32 + (c&1)*16 + ((c-32)>>1)
// h2 col c:        feature (c&1)*16 + (c>>1)
__device__ __forceinline__ int f1c(int c) {
    return (c < 32) ? ((c & 1) * 16 + (c >> 1)) : (32 + (c & 1) * 16 + ((c - 32) >> 1));
}
__device__ __forceinline__ int f2c(int c) { return (c & 1) * 16 + (c >> 1); }

#define H1C 72   // 64 + 8 pad cols (bf16) -> row stride 144 B (16B-aligned)
#define H2C 40   // 32 + 8  -> 80 B
#define H3C 24   // 16 + 8  -> 48 B

// r6 lesson: __launch_bounds__(256,3) under-allocated VGPRs -> hot-loop spills
// (FETCH 451 MB, 209 us). Plain 256 bound: allocator keeps live set resident.
__global__ __launch_bounds__(256)
void wd_fwd_v8(const int*   __restrict__ user_ids,
               const int*   __restrict__ movie_ids,
               const float* __restrict__ gender,
               const float* __restrict__ age,
               const float* __restrict__ occupation,
               const float* __restrict__ genres,
               const float* __restrict__ wide_W,
               const float* __restrict__ wide_b,
               const float* __restrict__ user_table,
               const float* __restrict__ movie_table,
               const float* __restrict__ W1,
               const float* __restrict__ b1,
               const float* __restrict__ W2,
               const float* __restrict__ b2,
               const float* __restrict__ W3,
               const float* __restrict__ b3,
               const float* __restrict__ W4,
               const float* __restrict__ b4,
               float*       __restrict__ out,
               int n)
{
    const int lane = threadIdx.x & 63;
    const int wib  = threadIdx.x >> 6;
    const int m    = lane & 15;
    const int quad = lane >> 4;

    __shared__ alignas(16) __bf16 sh1[4][16 * H1C];
    __shared__ alignas(16) __bf16 sh2[4][16 * H2C];
    __shared__ alignas(16) __bf16 sh3[4][16 * H3C];
    __bf16* __restrict__ h1p = sh1[wib];
    __bf16* __restrict__ h2p = sh2[wib];
    __bf16* __restrict__ h3p = sh3[wib];

    // ---------------- weight fragments (loop-invariant; exact RNE casts) ----
    // K-slot -> W1-row map for the rest K-tile (kt=2):
    // quad0: genres 0..7 (rows 67+j), quad1: genres 8..15 (75+j),
    // quad2: {g16,g17,gender,age,occ,synth,0,0} = rows {83,84,64,65,66,-2,-1,-1}, quad3: none.
    int restrow[8];
    #pragma unroll
    for (int j = 0; j < 8; ++j) {
        int r = -1;
        if (quad == 0) r = 67 + j;
        if (quad == 1) r = 75 + j;
        if (quad == 2) {
            if (j == 0) r = 83;
            else if (j == 1) r = 84;
            else if (j == 2) r = 64;
            else if (j == 3) r = 65;
            else if (j == 4) r = 66;
            else if (j == 5) r = -2;   // -2 = synthetic wide feature
            else r = -1;
        }
        restrow[j] = r;
    }

    bf16x8 B1f[3][4];
    #pragma unroll
    for (int kt = 0; kt < 2; ++kt)
        #pragma unroll
        for (int nt = 0; nt < 4; ++nt) {
            bf16x8 f;
            #pragma unroll
            for (int j = 0; j < 8; ++j)
                f[j] = (bf16_t)W1[(kt * 32 + quad * 8 + j) * H1N + nt * 16 + m];
            B1f[kt][nt] = f;
        }
    #pragma unroll
    for (int nt = 0; nt < 4; ++nt) {
        bf16x8 f;
        #pragma unroll
        for (int j = 0; j < 8; ++j)
            f[j] = (restrow[j] >= 0) ? (bf16_t)W1[restrow[j] * H1N + nt * 16 + m] : (bf16_t)0.0f;
        B1f[2][nt] = f;
    }
    bf16x8 Bwf;   // wide vector as 1-col B over the rest K-tile
    {
        const float* wr = wide_W + NUSERS + NMOVIES;
        #pragma unroll
        for (int j = 0; j < 8; ++j) {
            float v = 0.0f;
            if (m == 0) {
                if (restrow[j] >= 0)       v = wr[restrow[j] - 64];
                else if (restrow[j] == -2) v = 1.0f;
            }
            Bwf[j] = (bf16_t)v;
        }
    }
    bf16x8 B2f[2][2];
    #pragma unroll
    for (int kt = 0; kt < 2; ++kt)
        #pragma unroll
        for (int nt = 0; nt < 2; ++nt) {
            bf16x8 f;
            #pragma unroll
            for (int j = 0; j < 8; ++j)
                f[j] = (bf16_t)W2[f1c(kt * 32 + quad * 8 + j) * H2N + nt * 16 + m];
            B2f[kt][nt] = f;
        }
    bf16x8 B3f;
    #pragma unroll
    for (int j = 0; j < 8; ++j) B3f[j] = (bf16_t)W3[f2c(quad * 8 + j) * H3N + m];
    bf16x8 Bw4;   // layer-4 weights as 1-col B (K=32, upper 16 zero)
    #pragma unroll
    for (int j = 0; j < 8; ++j) {
        const int k = quad * 8 + j;
        Bw4[j] = (m == 0 && k < H3N) ? (bf16_t)W4[k] : (bf16_t)0.0f;
    }

    float bias1[4], bias2[2];
    #pragma unroll
    for (int nt = 0; nt < 4; ++nt) bias1[nt] = b1[nt * 16 + m];
    #pragma unroll
    for (int nt = 0; nt < 2; ++nt) bias2[nt] = b2[nt * 16 + m];
    const float bias3 = b3[m];
    const float wb0   = wide_b[0];
    f32x4 cw_init;    // layer-4/wide C seed: b4 on col 0
    {
        const float b4v = b4[0];
        #pragma unroll
        for (int r = 0; r < 4; ++r) cw_init[r] = (m == 0) ? b4v : 0.0f;
    }

    // ---------------- pipeline ----------------
    const int ntiles = (n + 15) >> 4;
    const int gwave  = blockIdx.x * 4 + wib;
    const int nwaves = gridDim.x * 4;
    int niter = (gwave < ntiles) ? (ntiles - gwave + nwaves - 1) / nwaves : 0;

#define LOAD_IDS(tt, U, M) { int rr_ = (tt) * 16 + m; rr_ = rr_ < n ? rr_ : n - 1; \
                             U = user_ids[rr_]; M = movie_ids[rr_]; }
#define PREFETCH(tt, UID, MID, U0, U1, M0, M1, PF) { \
    const float4* up_ = (const float4*)(user_table + (size_t)(UID) * EMB + quad * 8); \
    U0 = up_[0]; U1 = up_[1]; \
    const float4* mp_ = (const float4*)(movie_table + (size_t)(MID) * EMB + quad * 8); \
    M0 = mp_[0]; M1 = mp_[1]; \
    int rr_ = (tt) * 16 + m; rr_ = rr_ < n ? rr_ : n - 1; \
    const float* grow_ = genres + (size_t)rr_ * NGEN; \
    if (quad < 2) { \
        const float2* g2_ = (const float2*)(grow_ + quad * 8); \
        PF[0] = g2_[0]; PF[1] = g2_[1]; PF[2] = g2_[2]; PF[3] = g2_[3]; \
    } else if (quad == 2) { \
        PF[0] = ((const float2*)(grow_ + 16))[0]; \
        PF[1] = make_float2(gender[rr_], age[rr_]); \
        PF[2] = make_float2(occupation[rr_], wide_W[UID]); \
        PF[3] = make_float2(wide_W[NUSERS + (MID)], 0.0f); \
    } \
}

    if (niter > 0) {
        int t_c = gwave;
        int t_n = (niter > 1) ? t_c + nwaves : t_c;

        int uidc, midc, uidn, midn, uidn2, midn2;
        float4 U0c, U1c, M0c, M1c, U0n, U1n, M0n, M1n;
        float2 pfc[4] = {}, pfn[4] = {};

        LOAD_IDS(t_c, uidc, midc);
        LOAD_IDS(t_n, uidn, midn);
        PREFETCH(t_c, uidc, midc, U0c, U1c, M0c, M1c, pfc);
        uidn2 = uidn; midn2 = midn;

        for (int i = 0; i < niter; ++i) {
            const bool more = (i + 1 < niter);
            int t_n2 = t_n;
            if (more) {
                PREFETCH(t_n, uidn, midn, U0n, U1n, M0n, M1n, pfn);
                t_n2 = t_n + nwaves; if (t_n2 >= ntiles) t_n2 = t_n;
                LOAD_IDS(t_n2, uidn2, midn2);
            }

            // -------- compute tile t_c --------
            const int base = t_c << 4;

            bf16x8 A0 = mk8(U0c.x, U0c.y, U0c.z, U0c.w, U1c.x, U1c.y, U1c.z, U1c.w);
            bf16x8 A1 = mk8(M0c.x, M0c.y, M0c.z, M0c.w, M1c.x, M1c.y, M1c.z, M1c.w);
            bf16x8 A2;
            {
                float a0 = pfc[0].x, a1 = pfc[0].y, a2 = pfc[1].x, a3 = pfc[1].y;
                float a4 = pfc[2].x, a5 = pfc[2].y, a6 = pfc[3].x, a7 = pfc[3].y;
                if (quad == 2) { a5 = pfc[2].y + pfc[3].x + wb0; a6 = 0.0f; a7 = 0.0f; }
                if (quad == 3) { a0=a1=a2=a3=a4=a5=a6=a7 = 0.0f; }
                A2 = mk8(a0, a1, a2, a3, a4, a5, a6, a7);
            }

            // wide (+b4 seed) as 1-col MFMA on the rest K-tile
            f32x4 accw = mfma16(A2, Bwf, cw_init);

            // layer 1
            f32x4 acc[4];
            #pragma unroll
            for (int nt = 0; nt < 4; ++nt) {
                f32x4 c = {bias1[nt], bias1[nt], bias1[nt], bias1[nt]};
                c = mfma16(A0, B1f[0][nt], c);
                c = mfma16(A1, B1f[1][nt], c);
                c = mfma16(A2, B1f[2][nt], c);
                acc[nt] = c;
            }
            // relu + pack col-pairs -> bf16 LDS (8 b32 writes)
            #pragma unroll
            for (int r = 0; r < 4; ++r) {
                const int row = quad * 4 + r;
                *(unsigned*)&h1p[row * H1C + 2 * m] =
                    pkh(fmaxf(acc[0][r], 0.0f), fmaxf(acc[1][r], 0.0f));
                *(unsigned*)&h1p[row * H1C + 32 + 2 * m] =
                    pkh(fmaxf(acc[2][r], 0.0f), fmaxf(acc[3][r], 0.0f));
            }
            lds_fence();                 // order: h1 writes before h1 reads

            bf16x8 AL2[2];
            AL2[0] = *(const bf16x8*)&h1p[m * H1C + quad * 8];
            AL2[1] = *(const bf16x8*)&h1p[m * H1C + 32 + quad * 8];

            // layer 2
            f32x4 acc2[2];
            #pragma unroll
            for (int nt = 0; nt < 2; ++nt) {
                f32x4 c = {bias2[nt], bias2[nt], bias2[nt], bias2[nt]};
                c = mfma16(AL2[0], B2f[0][nt], c);
                c = mfma16(AL2[1], B2f[1][nt], c);
                acc2[nt] = c;
            }
            #pragma unroll
            for (int r = 0; r < 4; ++r) {
                const int row = quad * 4 + r;
                *(unsigned*)&h2p[row * H2C + 2 * m] =
                    pkh(fmaxf(acc2[0][r], 0.0f), fmaxf(acc2[1][r], 0.0f));
            }
            lds_fence();                 // order: h2 writes before h2 read

            bf16x8 AL3 = *(const bf16x8*)&h2p[m * H2C + quad * 8];

            // layer 3
            f32x4 acc3 = mfma16(AL3, B3f, (f32x4){bias3, bias3, bias3, bias3});
            #pragma unroll
            for (int r = 0; r < 4; ++r)
                *(unsigned short*)&h3p[(quad * 4 + r) * H3C + m] =
                    pks(fmaxf(acc3[r], 0.0f));
            lds_fence();                 // order: h3 writes before h3 read

            bf16x8 A4 = {};
            if (quad < 2) A4 = *(const bf16x8*)&h3p[m * H3C + quad * 8];
            lds_fence();                 // order: h3 read before next iter's writes

            // layer 4 + wide + b4 in one MFMA (C = accw)
            f32x4 z4 = mfma16(A4, Bw4, accw);

            if (m == 0) {
                const int ob = base + quad * 4;
                float4 o;
                o.x = 1.0f / (1.0f + __expf(-z4[0]));
                o.y = 1.0f / (1.0f + __expf(-z4[1]));
                o.z = 1.0f / (1.0f + __expf(-z4[2]));
                o.w = 1.0f / (1.0f + __expf(-z4[3]));
                if (ob + 3 < n) {
                    *(float4*)(out + ob) = o;
                } else {
                    if (ob     < n) out[ob]     = o.x;
                    if (ob + 1 < n) out[ob + 1] = o.y;
                    if (ob + 2 < n) out[ob + 2] = o.z;
                }
            }

            // -------- rotate pipeline --------
            if (more) {
                U0c = U0n; U1c = U1n; M0c = M0n; M1c = M1n;
                pfc[0] = pfn[0]; pfc[1] = pfn[1]; pfc[2] = pfn[2]; pfc[3] = pfn[3];
                uidn = uidn2; midn = midn2;
                t_c = t_n; t_n = t_n2;
            }
        }
    }
#undef LOAD_IDS
#undef PREFETCH
}

extern "C" void kernel_launch(void* const* d_in, const int* in_sizes, int n_in,
                              void* d_out, int out_size, void* d_ws, size_t ws_size,
                              hipStream_t stream)
{
    const int*   user_ids   = (const int*)  d_in[0];
    const int*   movie_ids  = (const int*)  d_in[1];
    const float* gender     = (const float*)d_in[2];
    const float* age        = (const float*)d_in[3];
    const float* occupation = (const float*)d_in[4];
    const float* genres     = (const float*)d_in[5];
    const float* wide_W     = (const float*)d_in[6];
    const float* wide_b     = (const float*)d_in[7];
    const float* user_table = (const float*)d_in[8];
    const float* movie_table= (const float*)d_in[9];
    const float* W1         = (const float*)d_in[10];
    const float* b1         = (const float*)d_in[11];
    const float* W2         = (const float*)d_in[12];
    const float* b2         = (const float*)d_in[13];
    const float* W3         = (const float*)d_in[14];
    const float* b3         = (const float*)d_in[15];
    const float* W4         = (const float*)d_in[16];
    const float* b4         = (const float*)d_in[17];
    float*       out        = (float*)d_out;

    const int n = in_sizes[0];
    wd_fwd_v8<<<1024, 256, 0, stream>>>(user_ids, movie_ids, gender, age, occupation,
                                        genres, wide_W, wide_b, user_table, movie_table,
                                        W1, b1, W2, b2, W3, b3, W4, b4, out, n);
}